// Round 1
// baseline (4735.856 us; speedup 1.0000x reference)
//
#include <hip/hip_runtime.h>
#include <hip/hip_bf16.h>

// Problem constants (static per reference)
#define B_  128
#define P_  196
#define ENCD 2048
#define A_  512
#define E_  512
#define D_  512
#define V_  10000
#define L_  22
#define T_  21

typedef __attribute__((ext_vector_type(8))) short short8;
typedef __attribute__((ext_vector_type(4))) float f32x4;

static __device__ __forceinline__ float bf2f(unsigned short u){
  union { unsigned int i; float f; } x; x.i = ((unsigned int)u) << 16; return x.f;
}
static __device__ __forceinline__ unsigned short f2bf(float f){
  union { float f; unsigned int i; } x; x.f = f;
  unsigned int r = x.i + 0x7fffu + ((x.i >> 16) & 1u);
  return (unsigned short)(r >> 16);
}

// ---------------------------------------------------------------------------
// Generic skinny GEMM: D[M,N] = A1[M,K1] @ B1[N,K1]^T (+ A2[M,K2] @ B2[N,K2]^T)
//                      (+ bias[n]) (+ C0[m*ldc0 + n]) (masked by lens/t)
// bf16 inputs, f32 accumulate. Wave computes 16x64 tile (4 accumulators).
// Block = 4 waves stacked in M (64x64 tile). M must be divisible by 64.
// ---------------------------------------------------------------------------
__global__ __launch_bounds__(256) void gemm_bt(
    const unsigned short* __restrict__ A1, int lda1,
    const unsigned short* __restrict__ B1, int ldb1, int K1,
    const unsigned short* __restrict__ A2, int lda2,
    const unsigned short* __restrict__ B2, int ldb2, int K2,
    const float* __restrict__ bias,
    const float* __restrict__ C0, long ldc0,
    float* __restrict__ outF, long ldo,
    unsigned short* __restrict__ outB, int ldob,
    const int* __restrict__ lens, int t,
    int N, int ntiles)
{
  int nt = blockIdx.x % ntiles;
  int mt = blockIdx.x / ntiles;
  int wave = threadIdx.x >> 6;
  int lane = threadIdx.x & 63;
  int quad = lane >> 4;
  int l16  = lane & 15;
  int m_row = mt*64 + wave*16 + l16;   // A row this lane loads
  int koff  = quad*8;
  int nf = (N - nt*64) >> 4; if (nf > 4) nf = 4;   // frags in N (tail tile)
  int nb0 = nt*64 + l16;

  f32x4 acc[4];
  #pragma unroll
  for (int f=0; f<4; ++f) acc[f] = (f32x4){0.f,0.f,0.f,0.f};

  const unsigned short* arow = A1 + (long)m_row*lda1 + koff;
  for (int k=0; k<K1; k+=32){
    short8 a = *(const short8*)(arow + k);
    #pragma unroll
    for (int f=0; f<4; ++f){
      if (f < nf){
        short8 b = *(const short8*)(B1 + (long)(nb0 + f*16)*ldb1 + k + koff);
        acc[f] = __builtin_amdgcn_mfma_f32_16x16x32_bf16(a, b, acc[f], 0, 0, 0);
      }
    }
  }
  if (K2 > 0){
    const unsigned short* arow2 = A2 + (long)m_row*lda2 + koff;
    for (int k=0; k<K2; k+=32){
      short8 a = *(const short8*)(arow2 + k);
      #pragma unroll
      for (int f=0; f<4; ++f){
        if (f < nf){
          short8 b = *(const short8*)(B2 + (long)(nb0 + f*16)*ldb2 + k + koff);
          acc[f] = __builtin_amdgcn_mfma_f32_16x16x32_bf16(a, b, acc[f], 0, 0, 0);
        }
      }
    }
  }

  // C/D layout (verified m89): col = lane&15, row = quad*4 + reg
  int m_base = mt*64 + wave*16 + quad*4;
  #pragma unroll
  for (int f=0; f<4; ++f){
    if (f >= nf) break;
    int n = nt*64 + f*16 + l16;
    float bv = bias ? bias[n] : 0.f;
    #pragma unroll
    for (int r=0; r<4; ++r){
      int m = m_base + r;
      float v = acc[f][r] + bv;
      if (C0) v += C0[(long)m*ldc0 + n];
      if (lens && !((lens[m]-1) > t)) v = 0.f;
      if (outF) outF[(long)m*ldo + n] = v;
      if (outB) outB[(long)m*ldob + n] = f2bf(v);
    }
  }
}

// ---------------------------------------------------------------------------
// encoder_out f32 -> bf16 copy + per-(b,c) mean over P (written as bf16)
// grid: 128 b * 8 chunks of 256 channels
// ---------------------------------------------------------------------------
__global__ __launch_bounds__(256) void enc_cvt_mean(
    const float* __restrict__ enc, unsigned short* __restrict__ enc_bf,
    unsigned short* __restrict__ mean_bf)
{
  int b = blockIdx.x >> 3;
  int c = (blockIdx.x & 7)*256 + threadIdx.x;
  long base = (long)b*P_*ENCD + c;
  float s = 0.f;
  for (int p=0; p<P_; ++p){
    float v = enc[base + (long)p*ENCD];
    s += v;
    enc_bf[base + (long)p*ENCD] = f2bf(v);
  }
  mean_bf[b*ENCD + c] = f2bf(s * (1.f/196.f));
}

__global__ __launch_bounds__(256) void cvt_bf16(
    const float* __restrict__ in, unsigned short* __restrict__ out, int n)
{
  for (int i = blockIdx.x*256 + threadIdx.x; i < n; i += gridDim.x*256)
    out[i] = f2bf(in[i]);
}

// split W_ih (2048 x 2560) into emb part (2048x512) and enc part (2048x2048), bf16
__global__ __launch_bounds__(256) void split_wih(
    const float* __restrict__ W, unsigned short* __restrict__ Wemb,
    unsigned short* __restrict__ Wenc)
{
  int j = blockIdx.x;
  for (int k = threadIdx.x; k < 2560; k += 256){
    unsigned short v = f2bf(W[(long)j*2560 + k]);
    if (k < 512) Wemb[j*512 + k] = v;
    else         Wenc[(long)j*2048 + (k-512)] = v;
  }
}

__global__ void add_bias2(const float* __restrict__ a, const float* __restrict__ b,
                          float* __restrict__ out, int n)
{
  int i = blockIdx.x*256 + threadIdx.x;
  if (i < n) out[i] = a[i] + b[i];
}

// X_emb[b*21+t, :] = bf16(E_emb[caps[b*22+t], :])
__global__ __launch_bounds__(256) void gather_emb(
    const int* __restrict__ caps, const float* __restrict__ E,
    unsigned short* __restrict__ X)
{
  int r = blockIdx.x;               // 0..2687
  int b = r / T_, t = r - b*T_;
  int tok = caps[b*L_ + t];
  for (int c = threadIdx.x; c < E_; c += 256)
    X[(long)r*E_ + c] = f2bf(E[(long)tok*E_ + c]);
}

// ---------------------------------------------------------------------------
// Per-step attention: e[b,p] = sum_a relu(att1[b,p,a] + att2[b,a]) * w[a] + bfull
// then softmax over p. Block per b, 4 waves over p.
// ---------------------------------------------------------------------------
__global__ __launch_bounds__(256) void attn_softmax(
    const unsigned short* __restrict__ att1, const float* __restrict__ att2,
    const float* __restrict__ w_full, const float* __restrict__ b_full,
    const int* __restrict__ lens, int t,
    float* __restrict__ alpha_ws, float* __restrict__ out_alpha, long ldo)
{
  __shared__ float att2s[A_];
  __shared__ float wfs[A_];
  __shared__ float ev[P_];
  __shared__ float red[8];
  int b = blockIdx.x, tid = threadIdx.x;
  for (int i = tid; i < A_; i += 256){ att2s[i] = att2[b*A_ + i]; wfs[i] = w_full[i]; }
  __syncthreads();
  int wave = tid >> 6, lane = tid & 63;
  for (int p = wave; p < P_; p += 4){
    const unsigned short* row = att1 + ((long)(b*P_ + p))*A_ + lane*8;
    short8 v = *(const short8*)row;
    float s = 0.f;
    #pragma unroll
    for (int i=0; i<8; ++i){
      float x = bf2f((unsigned short)v[i]) + att2s[lane*8 + i];
      x = fmaxf(x, 0.f);
      s += x * wfs[lane*8 + i];
    }
    #pragma unroll
    for (int off=32; off; off>>=1) s += __shfl_xor(s, off, 64);
    if (lane == 0) ev[p] = s + b_full[0];
  }
  __syncthreads();
  float v = (tid < P_) ? ev[tid] : -1e30f;
  #pragma unroll
  for (int off=32; off; off>>=1) v = fmaxf(v, __shfl_xor(v, off, 64));
  if (lane == 0) red[wave] = v;
  __syncthreads();
  float bmax = fmaxf(fmaxf(red[0], red[1]), fmaxf(red[2], red[3]));
  float ex = (tid < P_) ? __expf(ev[tid] - bmax) : 0.f;
  float s2 = ex;
  #pragma unroll
  for (int off=32; off; off>>=1) s2 += __shfl_xor(s2, off, 64);
  if (lane == 0) red[4 + wave] = s2;
  __syncthreads();
  float inv = 1.f / (red[4] + red[5] + red[6] + red[7]);
  if (tid < P_){
    float a = ex * inv;
    alpha_ws[b*P_ + tid] = a;                     // unmasked, feeds awe
    bool active = (lens[b] - 1) > t;
    out_alpha[(long)b*ldo + tid] = active ? a : 0.f;
  }
}

// awe[b,:] = sum_p alpha[b,p] * enc_bf[b,p,:]  -> bf16
// grid: 128 b * 4 chunks of 512 channels; thread handles 2 consecutive channels
__global__ __launch_bounds__(256) void awe_kernel(
    const unsigned short* __restrict__ enc_bf, const float* __restrict__ alpha,
    unsigned short* __restrict__ awe_bf)
{
  __shared__ float al[P_];
  int b = blockIdx.x >> 2;
  int chunk = blockIdx.x & 3;
  int tid = threadIdx.x;
  if (tid < P_) al[tid] = alpha[b*P_ + tid];
  __syncthreads();
  int c = chunk*512 + tid*2;
  long base = (long)b*P_*ENCD + c;
  float s0 = 0.f, s1 = 0.f;
  for (int p=0; p<P_; ++p){
    unsigned int u = *(const unsigned int*)(enc_bf + base + (long)p*ENCD);
    float a = al[p];
    s0 += a * bf2f((unsigned short)(u & 0xffffu));
    s1 += a * bf2f((unsigned short)(u >> 16));
  }
  unsigned int w = ((unsigned int)f2bf(s1) << 16) | f2bf(s0);
  *(unsigned int*)(awe_bf + (long)b*ENCD + c) = w;
}

// LSTM pointwise: gates [B,2048] -> h,c update with ragged mask; h also as bf16
__global__ __launch_bounds__(256) void lstm_update(
    const float* __restrict__ gates, float* __restrict__ h, float* __restrict__ c,
    unsigned short* __restrict__ h_bf, const int* __restrict__ lens, int t)
{
  int idx = blockIdx.x*256 + threadIdx.x;      // 65536
  int b = idx >> 9, d = idx & 511;
  const float* g = gates + (long)b*2048;
  float ii = g[d], ff = g[512 + d], gg = g[1024 + d], oo = g[1536 + d];
  float si = 1.f/(1.f + __expf(-ii));
  float sf = 1.f/(1.f + __expf(-ff));
  float so = 1.f/(1.f + __expf(-oo));
  float tg = tanhf(gg);
  float cn = sf*c[idx] + si*tg;
  float hn = so*tanhf(cn);
  bool active = (lens[b] - 1) > t;
  float h2 = active ? hn : h[idx];
  float c2 = active ? cn : c[idx];
  h[idx] = h2; c[idx] = c2; h_bf[idx] = f2bf(h2);
}

// ---------------------------------------------------------------------------
static inline void gemm_launch(hipStream_t s,
    const unsigned short* A1, int lda1, const unsigned short* B1, int ldb1, int K1,
    const unsigned short* A2, int lda2, const unsigned short* B2, int ldb2, int K2,
    const float* bias, const float* C0, long ldc0,
    float* outF, long ldo, unsigned short* outB, int ldob,
    const int* lens, int t, int M, int N)
{
  int mt = M / 64;
  int nt = (N + 63) / 64;
  gemm_bt<<<mt*nt, 256, 0, s>>>(A1, lda1, B1, ldb1, K1, A2, lda2, B2, ldb2, K2,
                                bias, C0, ldc0, outF, ldo, outB, ldob,
                                lens, t, N, nt);
}

extern "C" void kernel_launch(void* const* d_in, const int* in_sizes, int n_in,
                              void* d_out, int out_size, void* d_ws, size_t ws_size,
                              hipStream_t stream)
{
  const float* enc   = (const float*)d_in[0];
  const int*   caps  = (const int*)d_in[1];
  const int*   lens  = (const int*)d_in[2];
  const float* Eemb  = (const float*)d_in[3];
  const float* Wea   = (const float*)d_in[4];
  const float* bea   = (const float*)d_in[5];
  const float* Wda   = (const float*)d_in[6];
  const float* bda   = (const float*)d_in[7];
  const float* wfull = (const float*)d_in[8];
  const float* bfull = (const float*)d_in[9];
  const float* Wih0  = (const float*)d_in[10];
  const float* bih0  = (const float*)d_in[11];
  const float* Wic0  = (const float*)d_in[12];
  const float* bic0  = (const float*)d_in[13];
  const float* Wih   = (const float*)d_in[14];
  const float* bih   = (const float*)d_in[15];
  const float* Whh   = (const float*)d_in[16];
  const float* bhh   = (const float*)d_in[17];
  const float* Wfc   = (const float*)d_in[18];
  const float* bfc   = (const float*)d_in[19];

  // ---- workspace carve (~186 MB) ----
  char* wsp = (char*)d_ws;
  auto carve = [&](size_t bytes) -> char* {
    char* p = wsp; wsp += (bytes + 255) & ~(size_t)255; return p;
  };
  unsigned short* enc_bf   = (unsigned short*)carve((size_t)B_*P_*ENCD*2);   // 102.8 MB
  unsigned short* att1_bf  = (unsigned short*)carve((size_t)B_*P_*A_*2);     // 25.7 MB
  unsigned short* mean_bf  = (unsigned short*)carve((size_t)B_*ENCD*2);
  float*          gates_pre= (float*)carve((size_t)B_*T_*2048*4);            // 22 MB
  unsigned short* X_emb    = (unsigned short*)carve((size_t)B_*T_*E_*2);
  unsigned short* Wea_bf   = (unsigned short*)carve((size_t)A_*ENCD*2);
  unsigned short* Wda_bf   = (unsigned short*)carve((size_t)A_*D_*2);
  unsigned short* Wh0_bf   = (unsigned short*)carve((size_t)D_*ENCD*2);
  unsigned short* Wc0_bf   = (unsigned short*)carve((size_t)D_*ENCD*2);
  unsigned short* Whh_bf   = (unsigned short*)carve((size_t)2048*D_*2);
  unsigned short* Wie_bf   = (unsigned short*)carve((size_t)2048*E_*2);      // W_ih emb cols
  unsigned short* Wienc_bf = (unsigned short*)carve((size_t)2048*ENCD*2);    // W_ih enc cols
  unsigned short* Wfc_bf   = (unsigned short*)carve((size_t)V_*D_*2);        // 10.2 MB
  float*          bias_ifgo= (float*)carve((size_t)2048*4);
  float*          h        = (float*)carve((size_t)B_*D_*4);
  float*          c        = (float*)carve((size_t)B_*D_*4);
  unsigned short* h_bf     = (unsigned short*)carve((size_t)B_*D_*2);
  float*          att2     = (float*)carve((size_t)B_*A_*4);
  float*          alpha_ws = (float*)carve((size_t)B_*P_*4);
  unsigned short* awe_bf   = (unsigned short*)carve((size_t)B_*ENCD*2);
  float*          gates    = (float*)carve((size_t)B_*2048*4);

  float* out_preds  = (float*)d_out;                       // [B, T, V]
  float* out_alphas = (float*)d_out + (long)B_*T_*V_;      // [B, T, P]

  // ---- one-time per call: conversions + hoisted GEMMs ----
  enc_cvt_mean<<<1024, 256, 0, stream>>>(enc, enc_bf, mean_bf);
  cvt_bf16<<<1024, 256, 0, stream>>>(Wea,  Wea_bf, A_*ENCD);
  cvt_bf16<<<256,  256, 0, stream>>>(Wda,  Wda_bf, A_*D_);
  cvt_bf16<<<1024, 256, 0, stream>>>(Wih0, Wh0_bf, D_*ENCD);
  cvt_bf16<<<1024, 256, 0, stream>>>(Wic0, Wc0_bf, D_*ENCD);
  cvt_bf16<<<1024, 256, 0, stream>>>(Whh,  Whh_bf, 2048*D_);
  cvt_bf16<<<2048, 256, 0, stream>>>(Wfc,  Wfc_bf, V_*D_);
  split_wih<<<2048, 256, 0, stream>>>(Wih, Wie_bf, Wienc_bf);
  add_bias2<<<8, 256, 0, stream>>>(bih, bhh, bias_ifgo, 2048);
  gather_emb<<<B_*T_, 256, 0, stream>>>(caps, Eemb, X_emb);

  // h0 = mean @ W_init_h^T + b  (also bf16 copy); c0 likewise
  gemm_launch(stream, mean_bf, ENCD, Wh0_bf, ENCD, ENCD, 0,0,0,0,0,
              bih0, 0,0, h, D_, h_bf, D_, 0,0, B_, D_);
  gemm_launch(stream, mean_bf, ENCD, Wc0_bf, ENCD, ENCD, 0,0,0,0,0,
              bic0, 0,0, c, D_, 0,0, 0,0, B_, D_);
  // att1 = enc @ W_enc_att^T + b_enc_att  -> bf16 [B*P, A]
  gemm_launch(stream, enc_bf, ENCD, Wea_bf, ENCD, ENCD, 0,0,0,0,0,
              bea, 0,0, 0,0, att1_bf, A_, 0,0, B_*P_, A_);
  // gates_pre[b*T+t, :] = emb @ W_ih[:, :E]^T + b_ih + b_hh
  gemm_launch(stream, X_emb, E_, Wie_bf, E_, E_, 0,0,0,0,0,
              bias_ifgo, 0,0, gates_pre, 2048, 0,0, 0,0, B_*T_, 2048);

  // ---- decode loop (static T=21, fully unrolled into the graph) ----
  for (int t = 0; t < T_; ++t){
    // att2 = h @ W_dec_att^T + b_dec_att
    gemm_launch(stream, h_bf, D_, Wda_bf, D_, D_, 0,0,0,0,0,
                bda, 0,0, att2, A_, 0,0, 0,0, B_, A_);
    attn_softmax<<<B_, 256, 0, stream>>>(att1_bf, att2, wfull, bfull, lens, t,
                                         alpha_ws, out_alphas + (long)t*P_, (long)T_*P_);
    awe_kernel<<<B_*4, 256, 0, stream>>>(enc_bf, alpha_ws, awe_bf);
    // gates = h@W_hh^T + awe@W_ih[:,E:]^T + gates_pre[:,t,:]
    gemm_launch(stream, h_bf, D_, Whh_bf, D_, D_,
                awe_bf, ENCD, Wienc_bf, ENCD, ENCD,
                0, gates_pre + (long)t*2048, (long)T_*2048,
                gates, 2048, 0,0, 0,0, B_, 2048);
    lstm_update<<<B_*D_/256, 256, 0, stream>>>(gates, h, c, h_bf, lens, t);
    // preds[:, t, :] = mask * (h_new @ W_fc^T + b_fc)
    gemm_launch(stream, h_bf, D_, Wfc_bf, D_, D_, 0,0,0,0,0,
                bfc, 0,0, out_preds + (long)t*V_, (long)T_*V_, 0,0,
                lens, t, B_, V_);
  }
}

// Round 2
// 3243.781 us; speedup vs baseline: 1.4600x; 1.4600x over previous
//
#include <hip/hip_runtime.h>
#include <hip/hip_bf16.h>

// Problem constants (static per reference)
#define B_  128
#define P_  196
#define ENCD 2048
#define A_  512
#define E_  512
#define D_  512
#define V_  10000
#define L_  22
#define T_  21

typedef __attribute__((ext_vector_type(8))) short short8;
typedef __attribute__((ext_vector_type(4))) float f32x4;

static __device__ __forceinline__ float bf2f(unsigned short u){
  union { unsigned int i; float f; } x; x.i = ((unsigned int)u) << 16; return x.f;
}
static __device__ __forceinline__ unsigned short f2bf(float f){
  union { float f; unsigned int i; } x; x.f = f;
  unsigned int r = x.i + 0x7fffu + ((x.i >> 16) & 1u);
  return (unsigned short)(r >> 16);
}
static __device__ __forceinline__ unsigned int pack2(float a, float b){
  return (unsigned int)f2bf(a) | ((unsigned int)f2bf(b) << 16);
}
// async global->LDS, 16B per lane; LDS dest = wave-uniform base + lane*16
static __device__ __forceinline__ void glds16(const void* g, void* l){
  __builtin_amdgcn_global_load_lds((const __attribute__((address_space(1))) void*)g,
                                   (__attribute__((address_space(3))) void*)l, 16, 0, 0);
}

// ---------------------------------------------------------------------------
// m97-style 128x128-tile GEMM: C[M,N] = A[M,K] @ B[N,K]^T (+bias), bf16 in,
// f32 acc. M%128==0, N%128==0, K%32==0. Block=4 waves, each wave a 64x64
// quadrant (4x4 accs of 16x16x32). global_load_lds width=16 staging.
// ---------------------------------------------------------------------------
__global__ __launch_bounds__(256) void gemm128(
    const unsigned short* __restrict__ A, int lda,
    const unsigned short* __restrict__ B, int ldb, int K,
    const float* __restrict__ bias,
    float* __restrict__ outF, long ldo,
    unsigned short* __restrict__ outB, long ldob,
    int ntiles)
{
  __shared__ unsigned short As[128*32];
  __shared__ unsigned short Bs[128*32];
  int nt = blockIdx.x % ntiles, mt = blockIdx.x / ntiles;
  int tid = threadIdx.x, wave = tid >> 6, lane = tid & 63;
  int quad = lane >> 4, l16 = lane & 15;

  // staging: wave w stages tile rows [w*32, w*32+32), 2 issues of 16 rows.
  // lane l -> row w*32 + i*16 + (l>>2), 16B chunk (l&3). LDS dest is
  // contiguous: base(w,i) + lane*16 == row*64B + chunk*16B.  (m97 layout)
  const unsigned short* ga = A + (size_t)(mt*128 + wave*32 + (lane>>2))*lda + (lane&3)*8;
  const unsigned short* gb = B + (size_t)(nt*128 + wave*32 + (lane>>2))*ldb + (lane&3)*8;
  unsigned short* lA = &As[wave*32*32];
  unsigned short* lB = &Bs[wave*32*32];

  int wm = wave >> 1, wn = wave & 1;
  const unsigned short* rA = &As[(wm*64 + l16)*32 + quad*8];
  const unsigned short* rB = &Bs[(wn*64 + l16)*32 + quad*8];

  f32x4 acc[4][4];
  #pragma unroll
  for (int i=0;i<4;++i)
    #pragma unroll
    for (int j=0;j<4;++j) acc[i][j] = (f32x4){0.f,0.f,0.f,0.f};

  for (int k=0; k<K; k+=32){
    __syncthreads();
    glds16(ga + k,                    lA);
    glds16(ga + k + (size_t)16*lda,   lA + 16*32);
    glds16(gb + k,                    lB);
    glds16(gb + k + (size_t)16*ldb,   lB + 16*32);
    __syncthreads();   // compiler drains vmcnt(0) before s_barrier
    short8 af[4], bfr[4];
    #pragma unroll
    for (int i=0;i<4;++i) af[i]  = *(const short8*)(rA + i*16*32);
    #pragma unroll
    for (int i=0;i<4;++i) bfr[i] = *(const short8*)(rB + i*16*32);
    #pragma unroll
    for (int mf=0;mf<4;++mf)
      #pragma unroll
      for (int nf=0;nf<4;++nf)
        acc[mf][nf] = __builtin_amdgcn_mfma_f32_16x16x32_bf16(af[mf], bfr[nf], acc[mf][nf], 0,0,0);
  }

  // C/D layout: col = lane&15, row = quad*4 + r
  #pragma unroll
  for (int mf=0;mf<4;++mf){
    long mbase = mt*128 + wm*64 + mf*16 + quad*4;
    #pragma unroll
    for (int nf=0;nf<4;++nf){
      int col = nt*128 + wn*64 + nf*16 + l16;
      float bv = bias ? bias[col] : 0.f;
      #pragma unroll
      for (int r=0;r<4;++r){
        float v = acc[mf][nf][r] + bv;
        long m = mbase + r;
        if (outF) outF[m*ldo + col] = v;
        if (outB) outB[m*ldob + col] = f2bf(v);
      }
    }
  }
}

// ---------------------------------------------------------------------------
// Skinny-M GEMM with split-K across the 4 waves (16x64 output per block):
// D[M,N] = A1@B1^T (+ A2@B2^T) (+bias) (+C0) (masked). LDS-reduce at end.
// Grid = (M/16) * ceil(N/64) blocks -> 4x the parallelism of the old tiling.
// ---------------------------------------------------------------------------
__global__ __launch_bounds__(256) void gemm_sk(
    const unsigned short* __restrict__ A1, int lda1,
    const unsigned short* __restrict__ B1, int ldb1, int K1,
    const unsigned short* __restrict__ A2, int lda2,
    const unsigned short* __restrict__ B2, int ldb2, int K2,
    const float* __restrict__ bias,
    const float* __restrict__ C0, long ldc0,
    float* __restrict__ outF, long ldo,
    const int* __restrict__ lens, int t,
    int N, int ntiles)
{
  __shared__ float reds[3*64*16];
  int nt = blockIdx.x % ntiles, mt = blockIdx.x / ntiles;
  int tid = threadIdx.x, wave = tid >> 6, lane = tid & 63;
  int quad = lane >> 4, l16 = lane & 15;
  int m0 = mt*16;
  int nf = (N - nt*64) >> 4; if (nf > 4) nf = 4;
  int nb0 = nt*64 + l16;
  int Ktot = K1 + K2;
  int kc = ((Ktot + 127) >> 7) << 5;      // ceil(Ktot/128)*32
  int ks = wave*kc, ke = ks + kc; if (ke > Ktot) ke = Ktot;

  f32x4 acc[4];
  #pragma unroll
  for (int f=0;f<4;++f) acc[f] = (f32x4){0.f,0.f,0.f,0.f};

  for (int kk=ks; kk<ke; kk+=32){
    const unsigned short* Ap; const unsigned short* Bp; int k, lda, ldb;
    if (kk < K1){ Ap = A1; Bp = B1; k = kk;      lda = lda1; ldb = ldb1; }
    else        { Ap = A2; Bp = B2; k = kk - K1; lda = lda2; ldb = ldb2; }
    short8 a = *(const short8*)(Ap + (size_t)(m0 + l16)*lda + k + quad*8);
    #pragma unroll
    for (int f=0;f<4;++f){
      if (f < nf){
        short8 b = *(const short8*)(Bp + (size_t)(nb0 + f*16)*ldb + k + quad*8);
        acc[f] = __builtin_amdgcn_mfma_f32_16x16x32_bf16(a, b, acc[f], 0,0,0);
      }
    }
  }
  if (wave >= 1){
    float* dst = &reds[(wave-1)*1024 + lane*16];
    #pragma unroll
    for (int f=0;f<4;++f)
      #pragma unroll
      for (int r=0;r<4;++r) dst[f*4+r] = acc[f][r];
  }
  __syncthreads();
  if (wave == 0){
    #pragma unroll
    for (int w=0;w<3;++w){
      const float* src = &reds[w*1024 + lane*16];
      #pragma unroll
      for (int f=0;f<4;++f)
        #pragma unroll
        for (int r=0;r<4;++r) acc[f][r] += src[f*4+r];
    }
    #pragma unroll
    for (int f=0;f<4;++f){
      if (f >= nf) break;
      int n = nt*64 + f*16 + l16;
      float bv = bias ? bias[n] : 0.f;
      #pragma unroll
      for (int r=0;r<4;++r){
        long m = m0 + quad*4 + r;
        float v = acc[f][r] + bv;
        if (C0) v += C0[m*ldc0 + n];
        if (lens && !((lens[m]-1) > t)) v = 0.f;
        outF[m*ldo + n] = v;
      }
    }
  }
}

// ---------------------------------------------------------------------------
// Fused per-step attention: att2 = h@Wda^T+bda (VALU, f32 x bf16), then
// e/softmax over P, masked alpha out, then awe = alpha . enc (16B loads,
// p-unroll 4). One block per batch element.
// ---------------------------------------------------------------------------
__global__ __launch_bounds__(256) void att_fused(
    const float* __restrict__ h,
    const unsigned short* __restrict__ Wda,
    const float* __restrict__ bda,
    const unsigned short* __restrict__ att1,
    const float* __restrict__ wfull, const float* __restrict__ bfull,
    const unsigned short* __restrict__ enc_bf,
    const int* __restrict__ lens, int t,
    unsigned short* __restrict__ awe_bf,
    float* __restrict__ out_alpha, long ldo)
{
  __shared__ float hs[D_];
  __shared__ float att2s[A_];
  __shared__ float wfs[A_];
  __shared__ float als[P_];
  __shared__ float red[8];
  int b = blockIdx.x, tid = threadIdx.x;
  int wave = tid >> 6, lane = tid & 63;

  ((float2*)hs)[tid]  = ((const float2*)(h + (size_t)b*D_))[tid];
  ((float2*)wfs)[tid] = ((const float2*)wfull)[tid];
  __syncthreads();

  // att2 rows tid and tid+256
  {
    float s0 = 0.f, s1 = 0.f;
    const unsigned short* w0 = Wda + (size_t)tid*D_;
    const unsigned short* w1 = Wda + (size_t)(tid+256)*D_;
    for (int d=0; d<D_; d+=8){
      short8 va = *(const short8*)(w0 + d);
      short8 vb = *(const short8*)(w1 + d);
      #pragma unroll
      for (int j=0;j<8;++j){
        float hd = hs[d+j];
        s0 = fmaf(bf2f((unsigned short)va[j]), hd, s0);
        s1 = fmaf(bf2f((unsigned short)vb[j]), hd, s1);
      }
    }
    att2s[tid]     = s0 + bda[tid];
    att2s[tid+256] = s1 + bda[tid+256];
  }
  __syncthreads();

  // e[p] = sum_a relu(att1+att2)*wf + bfull
  for (int p = wave; p < P_; p += 4){
    short8 v = *(const short8*)(att1 + ((size_t)(b*P_ + p))*A_ + lane*8);
    float4 a20 = *(const float4*)(att2s + lane*8);
    float4 a21 = *(const float4*)(att2s + lane*8 + 4);
    float4 wf0 = *(const float4*)(wfs + lane*8);
    float4 wf1 = *(const float4*)(wfs + lane*8 + 4);
    float s = 0.f;
    s += fmaxf(bf2f((unsigned short)v[0]) + a20.x, 0.f) * wf0.x;
    s += fmaxf(bf2f((unsigned short)v[1]) + a20.y, 0.f) * wf0.y;
    s += fmaxf(bf2f((unsigned short)v[2]) + a20.z, 0.f) * wf0.z;
    s += fmaxf(bf2f((unsigned short)v[3]) + a20.w, 0.f) * wf0.w;
    s += fmaxf(bf2f((unsigned short)v[4]) + a21.x, 0.f) * wf1.x;
    s += fmaxf(bf2f((unsigned short)v[5]) + a21.y, 0.f) * wf1.y;
    s += fmaxf(bf2f((unsigned short)v[6]) + a21.z, 0.f) * wf1.z;
    s += fmaxf(bf2f((unsigned short)v[7]) + a21.w, 0.f) * wf1.w;
    #pragma unroll
    for (int off=32; off; off>>=1) s += __shfl_xor(s, off, 64);
    if (lane == 0) als[p] = s + bfull[0];
  }
  __syncthreads();
  float ev = (tid < P_) ? als[tid] : -1e30f;
  float mx = ev;
  #pragma unroll
  for (int off=32; off; off>>=1) mx = fmaxf(mx, __shfl_xor(mx, off, 64));
  if (lane == 0) red[wave] = mx;
  __syncthreads();
  float bmax = fmaxf(fmaxf(red[0],red[1]), fmaxf(red[2],red[3]));
  float ex = (tid < P_) ? __expf(ev - bmax) : 0.f;
  float sm = ex;
  #pragma unroll
  for (int off=32; off; off>>=1) sm += __shfl_xor(sm, off, 64);
  if (lane == 0) red[4+wave] = sm;
  __syncthreads();
  float inv = 1.f / (red[4]+red[5]+red[6]+red[7]);
  if (tid < P_){
    float alpha = ex * inv;
    als[tid] = alpha;                                  // unmasked, feeds awe
    bool active = (lens[b] - 1) > t;
    out_alpha[(size_t)b*ldo + tid] = active ? alpha : 0.f;
  }
  __syncthreads();

  // awe: thread -> 8 channels, 16B loads, p unrolled x4 (196 = 49*4)
  {
    int c0 = tid*8;
    const unsigned short* ep = enc_bf + (size_t)b*P_*ENCD + c0;
    float acc[8];
    #pragma unroll
    for (int j=0;j<8;++j) acc[j] = 0.f;
    for (int p=0; p<P_; p+=4){
      short8 e0 = *(const short8*)(ep + (size_t)(p+0)*ENCD);
      short8 e1 = *(const short8*)(ep + (size_t)(p+1)*ENCD);
      short8 e2 = *(const short8*)(ep + (size_t)(p+2)*ENCD);
      short8 e3 = *(const short8*)(ep + (size_t)(p+3)*ENCD);
      float a0 = als[p], a1 = als[p+1], a2 = als[p+2], a3 = als[p+3];
      #pragma unroll
      for (int j=0;j<8;++j){
        acc[j] = fmaf(bf2f((unsigned short)e0[j]), a0, acc[j]);
        acc[j] = fmaf(bf2f((unsigned short)e1[j]), a1, acc[j]);
        acc[j] = fmaf(bf2f((unsigned short)e2[j]), a2, acc[j]);
        acc[j] = fmaf(bf2f((unsigned short)e3[j]), a3, acc[j]);
      }
    }
    short8 o;
    #pragma unroll
    for (int j=0;j<8;++j) o[j] = (short)f2bf(acc[j]);
    *(short8*)(awe_bf + (size_t)b*ENCD + c0) = o;
  }
}

// LSTM pointwise
__global__ __launch_bounds__(256) void lstm_update(
    const float* __restrict__ gates, float* __restrict__ h, float* __restrict__ c,
    unsigned short* __restrict__ h_bf, const int* __restrict__ lens, int t)
{
  int idx = blockIdx.x*256 + threadIdx.x;      // 65536
  int b = idx >> 9, d = idx & 511;
  const float* g = gates + (size_t)b*2048;
  float ii = g[d], ff = g[512 + d], gg = g[1024 + d], oo = g[1536 + d];
  float si = 1.f/(1.f + __expf(-ii));
  float sf = 1.f/(1.f + __expf(-ff));
  float so = 1.f/(1.f + __expf(-oo));
  float tg = tanhf(gg);
  float cn = sf*c[idx] + si*tg;
  float hn = so*tanhf(cn);
  bool active = (lens[b] - 1) > t;
  float h2 = active ? hn : h[idx];
  float c2 = active ? cn : c[idx];
  h[idx] = h2; c[idx] = c2; h_bf[idx] = f2bf(h2);
}

// ---- one-time helpers ----
__global__ __launch_bounds__(256) void enc_cvt_mean(
    const float* __restrict__ enc, unsigned short* __restrict__ enc_bf,
    unsigned short* __restrict__ mean_bf)
{
  int b = blockIdx.x >> 1;
  int c = (blockIdx.x & 1)*1024 + threadIdx.x*4;
  size_t base = (size_t)b*P_*ENCD + c;
  float s0=0.f,s1=0.f,s2=0.f,s3=0.f;
  for (int p=0; p<P_; p+=2){
    float4 v0 = *(const float4*)(enc + base + (size_t)(p+0)*ENCD);
    float4 v1 = *(const float4*)(enc + base + (size_t)(p+1)*ENCD);
    s0 += v0.x + v1.x; s1 += v0.y + v1.y; s2 += v0.z + v1.z; s3 += v0.w + v1.w;
    uint2 r0; r0.x = pack2(v0.x, v0.y); r0.y = pack2(v0.z, v0.w);
    uint2 r1; r1.x = pack2(v1.x, v1.y); r1.y = pack2(v1.z, v1.w);
    *(uint2*)(enc_bf + base + (size_t)(p+0)*ENCD) = r0;
    *(uint2*)(enc_bf + base + (size_t)(p+1)*ENCD) = r1;
  }
  const float is = 1.f/196.f;
  uint2 m; m.x = pack2(s0*is, s1*is); m.y = pack2(s2*is, s3*is);
  *(uint2*)(mean_bf + (size_t)b*ENCD + c) = m;
}

__global__ __launch_bounds__(256) void cvt_bf16(
    const float* __restrict__ in, unsigned short* __restrict__ out, int n4)
{
  int i = blockIdx.x*256 + threadIdx.x;
  if (i < n4){
    float4 v = ((const float4*)in)[i];
    uint2 o; o.x = pack2(v.x, v.y); o.y = pack2(v.z, v.w);
    ((uint2*)out)[i] = o;
  }
}

__global__ __launch_bounds__(256) void split_wih(
    const float* __restrict__ W, unsigned short* __restrict__ Wemb,
    unsigned short* __restrict__ Wenc)
{
  int j = blockIdx.x;
  for (int k4 = threadIdx.x; k4 < 640; k4 += 256){
    float4 v = *(const float4*)(W + (size_t)j*2560 + k4*4);
    uint2 o; o.x = pack2(v.x, v.y); o.y = pack2(v.z, v.w);
    if (k4 < 128) *(uint2*)(Wemb + (size_t)j*512  + k4*4)        = o;
    else          *(uint2*)(Wenc + (size_t)j*2048 + (k4-128)*4)  = o;
  }
}

__global__ void add_bias2(const float* __restrict__ a, const float* __restrict__ b,
                          float* __restrict__ out, int n)
{
  int i = blockIdx.x*256 + threadIdx.x;
  if (i < n) out[i] = a[i] + b[i];
}

__global__ __launch_bounds__(128) void gather_emb(
    const int* __restrict__ caps, const float* __restrict__ E,
    unsigned short* __restrict__ X)
{
  int r = blockIdx.x;               // 0..2687
  int b = r / T_, t = r - b*T_;
  int tok = caps[b*L_ + t];
  int c = threadIdx.x*4;
  float4 v = *(const float4*)(E + (size_t)tok*E_ + c);
  uint2 o; o.x = pack2(v.x, v.y); o.y = pack2(v.z, v.w);
  *(uint2*)(X + (size_t)r*E_ + c) = o;
}

// ---------------------------------------------------------------------------
extern "C" void kernel_launch(void* const* d_in, const int* in_sizes, int n_in,
                              void* d_out, int out_size, void* d_ws, size_t ws_size,
                              hipStream_t stream)
{
  const float* enc   = (const float*)d_in[0];
  const int*   caps  = (const int*)d_in[1];
  const int*   lens  = (const int*)d_in[2];
  const float* Eemb  = (const float*)d_in[3];
  const float* Wea   = (const float*)d_in[4];
  const float* bea   = (const float*)d_in[5];
  const float* Wda   = (const float*)d_in[6];
  const float* bda   = (const float*)d_in[7];
  const float* wfull = (const float*)d_in[8];
  const float* bfull = (const float*)d_in[9];
  const float* Wih0  = (const float*)d_in[10];
  const float* bih0  = (const float*)d_in[11];
  const float* Wic0  = (const float*)d_in[12];
  const float* bic0  = (const float*)d_in[13];
  const float* Wih   = (const float*)d_in[14];
  const float* bih   = (const float*)d_in[15];
  const float* Whh   = (const float*)d_in[16];
  const float* bhh   = (const float*)d_in[17];
  const float* Wfc   = (const float*)d_in[18];
  const float* bfc   = (const float*)d_in[19];

  char* wsp = (char*)d_ws;
  auto carve = [&](size_t bytes) -> char* {
    char* p = wsp; wsp += (bytes + 255) & ~(size_t)255; return p;
  };
  unsigned short* enc_bf   = (unsigned short*)carve((size_t)B_*P_*ENCD*2);
  unsigned short* att1_bf  = (unsigned short*)carve((size_t)B_*P_*A_*2);
  unsigned short* mean_bf  = (unsigned short*)carve((size_t)B_*ENCD*2);
  float*          gates_pre= (float*)carve((size_t)B_*T_*2048*4);
  unsigned short* X_emb    = (unsigned short*)carve((size_t)B_*T_*E_*2);
  unsigned short* Wea_bf   = (unsigned short*)carve((size_t)A_*ENCD*2);
  unsigned short* Wda_bf   = (unsigned short*)carve((size_t)A_*D_*2);
  unsigned short* Wh0_bf   = (unsigned short*)carve((size_t)D_*ENCD*2);
  unsigned short* Wc0_bf   = (unsigned short*)carve((size_t)D_*ENCD*2);
  unsigned short* Whh_bf   = (unsigned short*)carve((size_t)2048*D_*2);
  unsigned short* Wie_bf   = (unsigned short*)carve((size_t)2048*E_*2);
  unsigned short* Wienc_bf = (unsigned short*)carve((size_t)2048*ENCD*2);
  unsigned short* Wfc_bf   = (unsigned short*)carve((size_t)V_*D_*2);
  float*          bias_ifgo= (float*)carve((size_t)2048*4);
  float*          h        = (float*)carve((size_t)B_*D_*4);
  float*          c        = (float*)carve((size_t)B_*D_*4);
  unsigned short* h_bf     = (unsigned short*)carve((size_t)B_*D_*2);
  unsigned short* awe_bf   = (unsigned short*)carve((size_t)B_*ENCD*2);
  float*          gates    = (float*)carve((size_t)B_*2048*4);

  float* out_preds  = (float*)d_out;                       // [B, T, V]
  float* out_alphas = (float*)d_out + (size_t)B_*T_*V_;    // [B, T, P]

  // ---- one-time conversions ----
  enc_cvt_mean<<<256, 256, 0, stream>>>(enc, enc_bf, mean_bf);
  cvt_bf16<<<1024, 256, 0, stream>>>(Wea,  Wea_bf, A_*ENCD/4);
  cvt_bf16<<<256,  256, 0, stream>>>(Wda,  Wda_bf, A_*D_/4);
  cvt_bf16<<<1024, 256, 0, stream>>>(Wih0, Wh0_bf, D_*ENCD/4);
  cvt_bf16<<<1024, 256, 0, stream>>>(Wic0, Wc0_bf, D_*ENCD/4);
  cvt_bf16<<<1024, 256, 0, stream>>>(Whh,  Whh_bf, 2048*D_/4);
  cvt_bf16<<<5000, 256, 0, stream>>>(Wfc,  Wfc_bf, V_*D_/4);
  split_wih<<<2048, 256, 0, stream>>>(Wih, Wie_bf, Wienc_bf);
  add_bias2<<<8, 256, 0, stream>>>(bih, bhh, bias_ifgo, 2048);
  gather_emb<<<B_*T_, 128, 0, stream>>>(caps, Eemb, X_emb);

  // ---- hoisted GEMMs (128-tile, global_load_lds) ----
  // h0 = mean @ W_init_h^T + b  (f32 + bf16); c0 likewise (f32 only)
  gemm128<<<1*4, 256, 0, stream>>>(mean_bf, ENCD, Wh0_bf, ENCD, ENCD,
                                   bih0, h, D_, h_bf, D_, 4);
  gemm128<<<1*4, 256, 0, stream>>>(mean_bf, ENCD, Wc0_bf, ENCD, ENCD,
                                   bic0, c, D_, (unsigned short*)0, 0, 4);
  // att1 = enc @ W_enc_att^T + b_enc_att -> bf16 [B*P, A]
  gemm128<<<196*4, 256, 0, stream>>>(enc_bf, ENCD, Wea_bf, ENCD, ENCD,
                                     bea, (float*)0, 0, att1_bf, A_, 4);
  // gates_pre = emb @ W_ih[:, :E]^T + (b_ih + b_hh)  [B*T, 2048]
  gemm128<<<21*16, 256, 0, stream>>>(X_emb, E_, Wie_bf, E_, E_,
                                     bias_ifgo, gates_pre, 2048, (unsigned short*)0, 0, 16);

  // ---- decode loop ----
  for (int t = 0; t < T_; ++t){
    att_fused<<<B_, 256, 0, stream>>>(h, Wda_bf, bda, att1_bf, wfull, bfull,
                                      enc_bf, lens, t, awe_bf,
                                      out_alphas + (size_t)t*P_, (long)T_*P_);
    // gates = h@W_hh^T + awe@W_ih[:,E:]^T + gates_pre[:,t,:]
    gemm_sk<<<8*32, 256, 0, stream>>>(h_bf, D_, Whh_bf, D_, D_,
                                      awe_bf, ENCD, Wienc_bf, ENCD, ENCD,
                                      (float*)0, gates_pre + (size_t)t*2048, (long)T_*2048,
                                      gates, 2048, (int*)0, t, 2048, 32);
    lstm_update<<<B_*D_/256, 256, 0, stream>>>(gates, h, c, h_bf, lens, t);
    // preds[:, t, :] = mask * (h_new @ W_fc^T + b_fc)
    gemm_sk<<<8*157, 256, 0, stream>>>(h_bf, D_, Wfc_bf, D_, D_,
                                       (unsigned short*)0, 0, (unsigned short*)0, 0, 0,
                                       bfc, (float*)0, 0,
                                       out_preds + (size_t)t*V_, (long)T_*V_,
                                       lens, t, V_, 157);
  }
}

// Round 3
// 2448.624 us; speedup vs baseline: 1.9341x; 1.3247x over previous
//
#include <hip/hip_runtime.h>
#include <hip/hip_bf16.h>

#define B_  128
#define P_  196
#define ENCD 2048
#define A_  512
#define E_  512
#define D_  512
#define V_  10000
#define L_  22
#define T_  21
#define VPAD 10112   // 79*128

typedef __attribute__((ext_vector_type(8))) short short8;
typedef __attribute__((ext_vector_type(4))) float f32x4;

static __device__ __forceinline__ float bf2f(unsigned short u){
  union { unsigned int i; float f; } x; x.i = ((unsigned int)u) << 16; return x.f;
}
static __device__ __forceinline__ unsigned short f2bf(float f){
  union { float f; unsigned int i; } x; x.f = f;
  unsigned int r = x.i + 0x7fffu + ((x.i >> 16) & 1u);
  return (unsigned short)(r >> 16);
}
static __device__ __forceinline__ unsigned int pack2(float a, float b){
  return (unsigned int)f2bf(a) | ((unsigned int)f2bf(b) << 16);
}
static __device__ __forceinline__ void glds16(const void* g, void* l){
  __builtin_amdgcn_global_load_lds((const __attribute__((address_space(1))) void*)g,
                                   (__attribute__((address_space(3))) void*)l, 16, 0, 0);
}

// ---------------------------------------------------------------------------
// 128x128-tile GEMM: C[M,N] = A[M,K] @ B[N,K]^T (+bias). bf16 in, f32 acc.
// M%128==0, N%128==0, K%32==0. XCD swizzle when grid%8==0 so blocks sharing
// an A-tile (consecutive ids) land on the same XCD's L2.
// ---------------------------------------------------------------------------
__global__ __launch_bounds__(256) void gemm128(
    const unsigned short* __restrict__ A, int lda,
    const unsigned short* __restrict__ B, int ldb, int K,
    const float* __restrict__ bias,
    float* __restrict__ outF, long ldo,
    unsigned short* __restrict__ outB, long ldob,
    int ntiles)
{
  __shared__ unsigned short As[128*32];
  __shared__ unsigned short Bs[128*32];
  int bid = blockIdx.x, nblk = gridDim.x;
  if ((nblk & 7) == 0){ int per = nblk >> 3; bid = (bid & 7)*per + (bid >> 3); }
  int nt = bid % ntiles, mt = bid / ntiles;
  int tid = threadIdx.x, wave = tid >> 6, lane = tid & 63;
  int quad = lane >> 4, l16 = lane & 15;

  const unsigned short* ga = A + (size_t)(mt*128 + wave*32 + (lane>>2))*lda + (lane&3)*8;
  const unsigned short* gb = B + (size_t)(nt*128 + wave*32 + (lane>>2))*ldb + (lane&3)*8;
  unsigned short* lA = &As[wave*32*32];
  unsigned short* lB = &Bs[wave*32*32];

  int wm = wave >> 1, wn = wave & 1;
  const unsigned short* rA = &As[(wm*64 + l16)*32 + quad*8];
  const unsigned short* rB = &Bs[(wn*64 + l16)*32 + quad*8];

  f32x4 acc[4][4];
  #pragma unroll
  for (int i=0;i<4;++i)
    #pragma unroll
    for (int j=0;j<4;++j) acc[i][j] = (f32x4){0.f,0.f,0.f,0.f};

  for (int k=0; k<K; k+=32){
    __syncthreads();
    glds16(ga + k,                    lA);
    glds16(ga + k + (size_t)16*lda,   lA + 16*32);
    glds16(gb + k,                    lB);
    glds16(gb + k + (size_t)16*ldb,   lB + 16*32);
    __syncthreads();
    short8 af[4], bfr[4];
    #pragma unroll
    for (int i=0;i<4;++i) af[i]  = *(const short8*)(rA + i*16*32);
    #pragma unroll
    for (int i=0;i<4;++i) bfr[i] = *(const short8*)(rB + i*16*32);
    #pragma unroll
    for (int mf=0;mf<4;++mf)
      #pragma unroll
      for (int nf=0;nf<4;++nf)
        acc[mf][nf] = __builtin_amdgcn_mfma_f32_16x16x32_bf16(af[mf], bfr[nf], acc[mf][nf], 0,0,0);
  }

  #pragma unroll
  for (int mf=0;mf<4;++mf){
    long mbase = mt*128 + wm*64 + mf*16 + quad*4;
    #pragma unroll
    for (int nf=0;nf<4;++nf){
      int col = nt*128 + wn*64 + nf*16 + l16;
      float bv = bias ? bias[col] : 0.f;
      #pragma unroll
      for (int r=0;r<4;++r){
        float v = acc[mf][nf][r] + bv;
        long m = mbase + r;
        if (outF) outF[m*ldo + col] = v;
        if (outB) outB[m*ldob + col] = f2bf(v);
      }
    }
  }
}

// ---------------------------------------------------------------------------
// Batched preds GEMM: A = h_bf_all[1..21] (M=2688), B = Wfc (padded to VPAD
// rows), K=512. Row m -> (t = m>>7, b = m&127); out row = b*21 + t, masked.
// ---------------------------------------------------------------------------
__global__ __launch_bounds__(256) void gemm_preds(
    const unsigned short* __restrict__ A,
    const unsigned short* __restrict__ B,
    const float* __restrict__ bias,
    const int* __restrict__ lens,
    float* __restrict__ out)
{
  __shared__ unsigned short As[128*32];
  __shared__ unsigned short Bs[128*32];
  int nt = blockIdx.x % 79, mt = blockIdx.x / 79;
  int tid = threadIdx.x, wave = tid >> 6, lane = tid & 63;
  int quad = lane >> 4, l16 = lane & 15;

  const unsigned short* ga = A + (size_t)(mt*128 + wave*32 + (lane>>2))*D_ + (lane&3)*8;
  const unsigned short* gb = B + (size_t)(nt*128 + wave*32 + (lane>>2))*D_ + (lane&3)*8;
  unsigned short* lA = &As[wave*32*32];
  unsigned short* lB = &Bs[wave*32*32];

  int wm = wave >> 1, wn = wave & 1;
  const unsigned short* rA = &As[(wm*64 + l16)*32 + quad*8];
  const unsigned short* rB = &Bs[(wn*64 + l16)*32 + quad*8];

  f32x4 acc[4][4];
  #pragma unroll
  for (int i=0;i<4;++i)
    #pragma unroll
    for (int j=0;j<4;++j) acc[i][j] = (f32x4){0.f,0.f,0.f,0.f};

  for (int k=0; k<D_; k+=32){
    __syncthreads();
    glds16(ga + k,                  lA);
    glds16(ga + k + (size_t)16*D_,  lA + 16*32);
    glds16(gb + k,                  lB);
    glds16(gb + k + (size_t)16*D_,  lB + 16*32);
    __syncthreads();
    short8 af[4], bfr[4];
    #pragma unroll
    for (int i=0;i<4;++i) af[i]  = *(const short8*)(rA + i*16*32);
    #pragma unroll
    for (int i=0;i<4;++i) bfr[i] = *(const short8*)(rB + i*16*32);
    #pragma unroll
    for (int mf=0;mf<4;++mf)
      #pragma unroll
      for (int nf=0;nf<4;++nf)
        acc[mf][nf] = __builtin_amdgcn_mfma_f32_16x16x32_bf16(af[mf], bfr[nf], acc[mf][nf], 0,0,0);
  }

  #pragma unroll
  for (int mf=0;mf<4;++mf){
    int mbase = mt*128 + wm*64 + mf*16 + quad*4;
    #pragma unroll
    for (int nf=0;nf<4;++nf){
      int col = nt*128 + wn*64 + nf*16 + l16;
      if (col >= V_) continue;
      float bv = bias[col];
      #pragma unroll
      for (int r=0;r<4;++r){
        int m = mbase + r;
        int tt = m >> 7, bb = m & 127;
        float v = ((lens[bb]-1) > tt) ? (acc[mf][nf][r] + bv) : 0.f;
        out[(size_t)(bb*T_ + tt)*V_ + col] = v;
      }
    }
  }
}

// ---------------------------------------------------------------------------
// Fused gates GEMM + LSTM pointwise.
// gates = hbf_prev@Whh^T + awe@Wienc^T + gates_pre[:,t,:]  (bias folded in)
// Block: mt in [0,8) rows (16 b's), nt in [0,32) cols (16 d's); the 4 frags
// are the four gate slices d, d+512, d+1024, d+1536. Split-K over 4 waves,
// LDS reduce, wave0 epilogue does sigmoid/tanh + c/h update + h_bf write.
// ---------------------------------------------------------------------------
__global__ __launch_bounds__(256) void gemm_gates(
    const unsigned short* __restrict__ hbf_prev,
    const unsigned short* __restrict__ Whh,
    const unsigned short* __restrict__ awe,
    const unsigned short* __restrict__ Wienc,
    const float* __restrict__ gates_pre,
    float* __restrict__ h, float* __restrict__ c,
    unsigned short* __restrict__ hbf_out,
    const int* __restrict__ lens, int t)
{
  __shared__ float reds[3*64*16];
  int nt = blockIdx.x & 31, mt = blockIdx.x >> 5;
  int tid = threadIdx.x, wave = tid >> 6, lane = tid & 63;
  int quad = lane >> 4, l16 = lane & 15;
  int m0 = mt*16;
  int ks = wave*640, ke = ks + 640;      // Ktot = 512 + 2048

  f32x4 acc[4];
  #pragma unroll
  for (int f=0;f<4;++f) acc[f] = (f32x4){0.f,0.f,0.f,0.f};

  for (int kk=ks; kk<ke; kk+=32){
    const unsigned short* Ap; const unsigned short* Bp; int k, lda, ldb;
    if (kk < 512){ Ap = hbf_prev; Bp = Whh;   k = kk;       lda = 512;  ldb = 512;  }
    else         { Ap = awe;      Bp = Wienc; k = kk - 512; lda = 2048; ldb = 2048; }
    short8 a = *(const short8*)(Ap + (size_t)(m0 + l16)*lda + k + quad*8);
    #pragma unroll
    for (int f=0;f<4;++f){
      short8 b = *(const short8*)(Bp + (size_t)(nt*16 + f*512 + l16)*ldb + k + quad*8);
      acc[f] = __builtin_amdgcn_mfma_f32_16x16x32_bf16(a, b, acc[f], 0,0,0);
    }
  }
  if (wave >= 1){
    float* dst = &reds[(wave-1)*1024 + lane*16];
    #pragma unroll
    for (int f=0;f<4;++f)
      #pragma unroll
      for (int r=0;r<4;++r) dst[f*4+r] = acc[f][r];
  }
  __syncthreads();
  if (wave == 0){
    #pragma unroll
    for (int w=0;w<3;++w){
      const float* src = &reds[w*1024 + lane*16];
      #pragma unroll
      for (int f=0;f<4;++f)
        #pragma unroll
        for (int r=0;r<4;++r) acc[f][r] += src[f*4+r];
    }
    int d = nt*16 + l16;
    #pragma unroll
    for (int r=0;r<4;++r){
      int m = m0 + quad*4 + r;                  // batch index
      const float* gp = gates_pre + ((size_t)m*T_ + t)*2048;
      float vi = acc[0][r] + gp[d];
      float vf = acc[1][r] + gp[512 + d];
      float vg = acc[2][r] + gp[1024 + d];
      float vo = acc[3][r] + gp[1536 + d];
      float si = 1.f/(1.f + __expf(-vi));
      float sf = 1.f/(1.f + __expf(-vf));
      float so = 1.f/(1.f + __expf(-vo));
      float tg = tanhf(vg);
      int idx = m*512 + d;
      float cn = sf*c[idx] + si*tg;
      float hn = so*tanhf(cn);
      bool active = (lens[m] - 1) > t;
      float h2 = active ? hn : h[idx];
      float c2 = active ? cn : c[idx];
      h[idx] = h2; c[idx] = c2; hbf_out[idx] = f2bf(h2);
    }
  }
}

// ---------------------------------------------------------------------------
// Fused per-step attention: att2 = h@Wda^T + bda, e/softmax over P, masked
// alpha out, awe = alpha . enc. One block per batch element.
// ---------------------------------------------------------------------------
__global__ __launch_bounds__(256) void att_fused(
    const float* __restrict__ h,
    const unsigned short* __restrict__ Wda,
    const float* __restrict__ bda,
    const unsigned short* __restrict__ att1,
    const float* __restrict__ wfull, const float* __restrict__ bfull,
    const unsigned short* __restrict__ enc_bf,
    const int* __restrict__ lens, int t,
    unsigned short* __restrict__ awe_bf,
    float* __restrict__ out_alpha, long ldo)
{
  __shared__ float hs[D_];
  __shared__ float att2s[A_];
  __shared__ float wfs[A_];
  __shared__ float als[P_];
  __shared__ float red[8];
  int b = blockIdx.x, tid = threadIdx.x;
  int wave = tid >> 6, lane = tid & 63;

  ((float2*)hs)[tid]  = ((const float2*)(h + (size_t)b*D_))[tid];
  ((float2*)wfs)[tid] = ((const float2*)wfull)[tid];
  __syncthreads();

  {
    float s0 = 0.f, s1 = 0.f;
    const unsigned short* w0 = Wda + (size_t)tid*D_;
    const unsigned short* w1 = Wda + (size_t)(tid+256)*D_;
    for (int d=0; d<D_; d+=8){
      short8 va = *(const short8*)(w0 + d);
      short8 vb = *(const short8*)(w1 + d);
      #pragma unroll
      for (int j=0;j<8;++j){
        float hd = hs[d+j];
        s0 = fmaf(bf2f((unsigned short)va[j]), hd, s0);
        s1 = fmaf(bf2f((unsigned short)vb[j]), hd, s1);
      }
    }
    att2s[tid]     = s0 + bda[tid];
    att2s[tid+256] = s1 + bda[tid+256];
  }
  __syncthreads();

  for (int p = wave; p < P_; p += 4){
    short8 v = *(const short8*)(att1 + ((size_t)(b*P_ + p))*A_ + lane*8);
    float4 a20 = *(const float4*)(att2s + lane*8);
    float4 a21 = *(const float4*)(att2s + lane*8 + 4);
    float4 wf0 = *(const float4*)(wfs + lane*8);
    float4 wf1 = *(const float4*)(wfs + lane*8 + 4);
    float s = 0.f;
    s += fmaxf(bf2f((unsigned short)v[0]) + a20.x, 0.f) * wf0.x;
    s += fmaxf(bf2f((unsigned short)v[1]) + a20.y, 0.f) * wf0.y;
    s += fmaxf(bf2f((unsigned short)v[2]) + a20.z, 0.f) * wf0.z;
    s += fmaxf(bf2f((unsigned short)v[3]) + a20.w, 0.f) * wf0.w;
    s += fmaxf(bf2f((unsigned short)v[4]) + a21.x, 0.f) * wf1.x;
    s += fmaxf(bf2f((unsigned short)v[5]) + a21.y, 0.f) * wf1.y;
    s += fmaxf(bf2f((unsigned short)v[6]) + a21.z, 0.f) * wf1.z;
    s += fmaxf(bf2f((unsigned short)v[7]) + a21.w, 0.f) * wf1.w;
    #pragma unroll
    for (int off=32; off; off>>=1) s += __shfl_xor(s, off, 64);
    if (lane == 0) als[p] = s + bfull[0];
  }
  __syncthreads();
  float ev = (tid < P_) ? als[tid] : -1e30f;
  float mx = ev;
  #pragma unroll
  for (int off=32; off; off>>=1) mx = fmaxf(mx, __shfl_xor(mx, off, 64));
  if (lane == 0) red[wave] = mx;
  __syncthreads();
  float bmax = fmaxf(fmaxf(red[0],red[1]), fmaxf(red[2],red[3]));
  float ex = (tid < P_) ? __expf(ev - bmax) : 0.f;
  float sm = ex;
  #pragma unroll
  for (int off=32; off; off>>=1) sm += __shfl_xor(sm, off, 64);
  if (lane == 0) red[4+wave] = sm;
  __syncthreads();
  float inv = 1.f / (red[4]+red[5]+red[6]+red[7]);
  if (tid < P_){
    float alpha = ex * inv;
    als[tid] = alpha;
    bool active = (lens[b] - 1) > t;
    out_alpha[(size_t)b*ldo + tid] = active ? alpha : 0.f;
  }
  __syncthreads();

  {
    int c0 = tid*8;
    const unsigned short* ep = enc_bf + (size_t)b*P_*ENCD + c0;
    float acc[8];
    #pragma unroll
    for (int j=0;j<8;++j) acc[j] = 0.f;
    for (int p=0; p<P_; p+=4){
      short8 e0 = *(const short8*)(ep + (size_t)(p+0)*ENCD);
      short8 e1 = *(const short8*)(ep + (size_t)(p+1)*ENCD);
      short8 e2 = *(const short8*)(ep + (size_t)(p+2)*ENCD);
      short8 e3 = *(const short8*)(ep + (size_t)(p+3)*ENCD);
      float a0 = als[p], a1 = als[p+1], a2 = als[p+2], a3 = als[p+3];
      #pragma unroll
      for (int j=0;j<8;++j){
        acc[j] = fmaf(bf2f((unsigned short)e0[j]), a0, acc[j]);
        acc[j] = fmaf(bf2f((unsigned short)e1[j]), a1, acc[j]);
        acc[j] = fmaf(bf2f((unsigned short)e2[j]), a2, acc[j]);
        acc[j] = fmaf(bf2f((unsigned short)e3[j]), a3, acc[j]);
      }
    }
    short8 o;
    #pragma unroll
    for (int j=0;j<8;++j) o[j] = (short)f2bf(acc[j]);
    *(short8*)(awe_bf + (size_t)b*ENCD + c0) = o;
  }
}

// ---- one-time helpers ----
__global__ __launch_bounds__(256) void enc_cvt_mean(
    const float* __restrict__ enc, unsigned short* __restrict__ enc_bf,
    unsigned short* __restrict__ mean_bf)
{
  int b = blockIdx.x >> 1;
  int c = (blockIdx.x & 1)*1024 + threadIdx.x*4;
  size_t base = (size_t)b*P_*ENCD + c;
  float s0=0.f,s1=0.f,s2=0.f,s3=0.f;
  for (int p=0; p<P_; p+=2){
    float4 v0 = *(const float4*)(enc + base + (size_t)(p+0)*ENCD);
    float4 v1 = *(const float4*)(enc + base + (size_t)(p+1)*ENCD);
    s0 += v0.x + v1.x; s1 += v0.y + v1.y; s2 += v0.z + v1.z; s3 += v0.w + v1.w;
    uint2 r0; r0.x = pack2(v0.x, v0.y); r0.y = pack2(v0.z, v0.w);
    uint2 r1; r1.x = pack2(v1.x, v1.y); r1.y = pack2(v1.z, v1.w);
    *(uint2*)(enc_bf + base + (size_t)(p+0)*ENCD) = r0;
    *(uint2*)(enc_bf + base + (size_t)(p+1)*ENCD) = r1;
  }
  const float is = 1.f/196.f;
  uint2 m; m.x = pack2(s0*is, s1*is); m.y = pack2(s2*is, s3*is);
  *(uint2*)(mean_bf + (size_t)b*ENCD + c) = m;
}

__global__ __launch_bounds__(256) void cvt_bf16(
    const float* __restrict__ in, unsigned short* __restrict__ out, int n4)
{
  int i = blockIdx.x*256 + threadIdx.x;
  if (i < n4){
    float4 v = ((const float4*)in)[i];
    uint2 o; o.x = pack2(v.x, v.y); o.y = pack2(v.z, v.w);
    ((uint2*)out)[i] = o;
  }
}

__global__ __launch_bounds__(256) void split_wih(
    const float* __restrict__ W, unsigned short* __restrict__ Wemb,
    unsigned short* __restrict__ Wenc)
{
  int j = blockIdx.x;
  for (int k4 = threadIdx.x; k4 < 640; k4 += 256){
    float4 v = *(const float4*)(W + (size_t)j*2560 + k4*4);
    uint2 o; o.x = pack2(v.x, v.y); o.y = pack2(v.z, v.w);
    if (k4 < 128) *(uint2*)(Wemb + (size_t)j*512  + k4*4)        = o;
    else          *(uint2*)(Wenc + (size_t)j*2048 + (k4-128)*4)  = o;
  }
}

__global__ void add_bias2(const float* __restrict__ a, const float* __restrict__ b,
                          float* __restrict__ out, int n)
{
  int i = blockIdx.x*256 + threadIdx.x;
  if (i < n) out[i] = a[i] + b[i];
}

__global__ __launch_bounds__(128) void gather_emb(
    const int* __restrict__ caps, const float* __restrict__ E,
    unsigned short* __restrict__ X)
{
  int r = blockIdx.x;
  int b = r / T_, t = r - b*T_;
  int tok = caps[b*L_ + t];
  int c = threadIdx.x*4;
  float4 v = *(const float4*)(E + (size_t)tok*E_ + c);
  uint2 o; o.x = pack2(v.x, v.y); o.y = pack2(v.z, v.w);
  *(uint2*)(X + (size_t)r*E_ + c) = o;
}

// ---------------------------------------------------------------------------
extern "C" void kernel_launch(void* const* d_in, const int* in_sizes, int n_in,
                              void* d_out, int out_size, void* d_ws, size_t ws_size,
                              hipStream_t stream)
{
  const float* enc   = (const float*)d_in[0];
  const int*   caps  = (const int*)d_in[1];
  const int*   lens  = (const int*)d_in[2];
  const float* Eemb  = (const float*)d_in[3];
  const float* Wea   = (const float*)d_in[4];
  const float* bea   = (const float*)d_in[5];
  const float* Wda   = (const float*)d_in[6];
  const float* bda   = (const float*)d_in[7];
  const float* wfull = (const float*)d_in[8];
  const float* bfull = (const float*)d_in[9];
  const float* Wih0  = (const float*)d_in[10];
  const float* bih0  = (const float*)d_in[11];
  const float* Wic0  = (const float*)d_in[12];
  const float* bic0  = (const float*)d_in[13];
  const float* Wih   = (const float*)d_in[14];
  const float* bih   = (const float*)d_in[15];
  const float* Whh   = (const float*)d_in[16];
  const float* bhh   = (const float*)d_in[17];
  const float* Wfc   = (const float*)d_in[18];
  const float* bfc   = (const float*)d_in[19];

  char* wsp = (char*)d_ws;
  auto carve = [&](size_t bytes) -> char* {
    char* p = wsp; wsp += (bytes + 255) & ~(size_t)255; return p;
  };
  unsigned short* enc_bf   = (unsigned short*)carve((size_t)B_*P_*ENCD*2);
  unsigned short* att1_bf  = (unsigned short*)carve((size_t)B_*P_*A_*2);
  unsigned short* mean_bf  = (unsigned short*)carve((size_t)B_*ENCD*2);
  float*          gates_pre= (float*)carve((size_t)B_*T_*2048*4);
  unsigned short* X_emb    = (unsigned short*)carve((size_t)B_*T_*E_*2);
  unsigned short* Wea_bf   = (unsigned short*)carve((size_t)A_*ENCD*2);
  unsigned short* Wda_bf   = (unsigned short*)carve((size_t)A_*D_*2);
  unsigned short* Wh0_bf   = (unsigned short*)carve((size_t)D_*ENCD*2);
  unsigned short* Wc0_bf   = (unsigned short*)carve((size_t)D_*ENCD*2);
  unsigned short* Whh_bf   = (unsigned short*)carve((size_t)2048*D_*2);
  unsigned short* Wie_bf   = (unsigned short*)carve((size_t)2048*E_*2);
  unsigned short* Wienc_bf = (unsigned short*)carve((size_t)2048*ENCD*2);
  unsigned short* Wfc_bf   = (unsigned short*)carve((size_t)VPAD*D_*2);
  float*          bias_ifgo= (float*)carve((size_t)2048*4);
  float*          h        = (float*)carve((size_t)B_*D_*4);
  float*          c        = (float*)carve((size_t)B_*D_*4);
  unsigned short* h_bf_all = (unsigned short*)carve((size_t)(T_+1)*B_*D_*2);
  unsigned short* awe_bf   = (unsigned short*)carve((size_t)B_*ENCD*2);

  float* out_preds  = (float*)d_out;                       // [B, T, V]
  float* out_alphas = (float*)d_out + (size_t)B_*T_*V_;    // [B, T, P]

  // ---- one-time conversions ----
  enc_cvt_mean<<<256, 256, 0, stream>>>(enc, enc_bf, mean_bf);
  cvt_bf16<<<1024, 256, 0, stream>>>(Wea,  Wea_bf, A_*ENCD/4);
  cvt_bf16<<<256,  256, 0, stream>>>(Wda,  Wda_bf, A_*D_/4);
  cvt_bf16<<<1024, 256, 0, stream>>>(Wih0, Wh0_bf, D_*ENCD/4);
  cvt_bf16<<<1024, 256, 0, stream>>>(Wic0, Wc0_bf, D_*ENCD/4);
  cvt_bf16<<<1024, 256, 0, stream>>>(Whh,  Whh_bf, 2048*D_/4);
  cvt_bf16<<<5000, 256, 0, stream>>>(Wfc,  Wfc_bf, V_*D_/4);
  split_wih<<<2048, 256, 0, stream>>>(Wih, Wie_bf, Wienc_bf);
  add_bias2<<<8, 256, 0, stream>>>(bih, bhh, bias_ifgo, 2048);
  gather_emb<<<B_*T_, 128, 0, stream>>>(caps, Eemb, X_emb);

  // ---- hoisted GEMMs ----
  gemm128<<<1*4, 256, 0, stream>>>(mean_bf, ENCD, Wh0_bf, ENCD, ENCD,
                                   bih0, h, D_, h_bf_all, D_, 4);         // h0 (slot 0)
  gemm128<<<1*4, 256, 0, stream>>>(mean_bf, ENCD, Wc0_bf, ENCD, ENCD,
                                   bic0, c, D_, (unsigned short*)0, 0, 4); // c0
  gemm128<<<196*4, 256, 0, stream>>>(enc_bf, ENCD, Wea_bf, ENCD, ENCD,
                                     bea, (float*)0, 0, att1_bf, A_, 4);   // att1
  gemm128<<<21*16, 256, 0, stream>>>(X_emb, E_, Wie_bf, E_, E_,
                                     bias_ifgo, gates_pre, 2048, (unsigned short*)0, 0, 16);

  // ---- decode loop: 2 kernels per step ----
  for (int t = 0; t < T_; ++t){
    att_fused<<<B_, 256, 0, stream>>>(h, Wda_bf, bda, att1_bf, wfull, bfull,
                                      enc_bf, lens, t, awe_bf,
                                      out_alphas + (size_t)t*P_, (long)T_*P_);
    gemm_gates<<<256, 256, 0, stream>>>(h_bf_all + (size_t)t*B_*D_, Whh_bf,
                                        awe_bf, Wienc_bf, gates_pre,
                                        h, c, h_bf_all + (size_t)(t+1)*B_*D_,
                                        lens, t);
  }

  // ---- batched preds GEMM over all steps ----
  gemm_preds<<<21*79, 256, 0, stream>>>(h_bf_all + (size_t)B_*D_, Wfc_bf,
                                        bfc, lens, out_preds);
}